// Round 1
// baseline (2542.998 us; speedup 1.0000x reference)
//
#include <hip/hip_runtime.h>

#define NB 8192      // batch
#define DD 32        // dims
#define KB 8         // spline bins
#define NH 256       // hidden
#define PER 25       // 3*K+1
#define RT 16        // rows per block

__device__ __forceinline__ float gelu_f(float x) {
    float x3 = x * x * x;
    return 0.5f * x * (1.0f + tanhf(0.7978845608028654f * (x + 0.044715f * x3)));
}
__device__ __forceinline__ float softplus_f(float x) {
    return (x > 20.0f) ? x : log1pf(expf(x));
}

// Materialize masked weights into ws; zero the ldj accumulator region of d_out.
__global__ void prep_kernel(const float* __restrict__ W0, const float* __restrict__ W1,
                            const float* __restrict__ Wout,
                            float* __restrict__ W0m, float* __restrict__ W1m,
                            float* __restrict__ Woutm, float* __restrict__ ldj)
{
    int n = blockIdx.x * blockDim.x + threadIdx.x;
    if (n < NB) ldj[n] = 0.0f;
    const int total = 8192 + 65536 + 204800;
    for (int idx = n; idx < total; idx += gridDim.x * blockDim.x) {
        if (idx < 8192) {
            int d = idx >> 8, j = idx & 255;            // W0: (32,256)
            W0m[idx] = (((j % 31) + 1) >= (d + 1)) ? W0[idx] : 0.0f;
        } else if (idx < 8192 + 65536) {
            int m = idx - 8192;
            int a = m >> 8, j = m & 255;                // W1: (256,256)
            W1m[m] = ((j % 31) >= (a % 31)) ? W1[m] : 0.0f;
        } else {
            int m = idx - (8192 + 65536);
            int r = m >> 8, j = m & 255;                // W_out: (800,256)
            int i = r / PER;
            Woutm[m] = (i > (j % 31)) ? Wout[m] : 0.0f; // (i+1) > hd1[j]
        }
    }
}

// One autoregressive step: compute MADE for dim i on all rows, invert spline, write x[:,i], ldj +=.
__global__ __launch_bounds__(256) void step_kernel(
    int i, const float* __restrict__ z,
    const float* __restrict__ W0m, const float* __restrict__ b0,
    const float* __restrict__ W1m, const float* __restrict__ b1,
    const float* __restrict__ Woutm, const float* __restrict__ b_out,
    const int* __restrict__ tstep_p,
    float* __restrict__ xout, float* __restrict__ ldj)
{
    __shared__ __align__(16) float sh0[RT * NH];   // h0 tile; later reused for p
    __shared__ __align__(16) float sh1[RT * NH];   // x tile (prefix), then h1 tile
    const int t = threadIdx.x;
    const int row0 = blockIdx.x * RT;

    // stage x tile (RT x 32) into sh1 front
    *(float2*)&sh1[t * 2] = *(const float2*)&xout[row0 * DD + t * 2];
    __syncthreads();

    const int c0 = (t & 63) * 4;    // 4 columns per thread
    const int r0 = (t >> 6) * 4;    // 4 rows per thread

    float4 acc[4];

    // ---- GEMM1: h0 = gelu(x @ W0m + b0) ----
#pragma unroll
    for (int rr = 0; rr < 4; ++rr) acc[rr] = make_float4(0.f, 0.f, 0.f, 0.f);
#pragma unroll
    for (int kg = 0; kg < DD; kg += 4) {
        float4 w0 = *(const float4*)&W0m[(kg + 0) * NH + c0];
        float4 w1 = *(const float4*)&W0m[(kg + 1) * NH + c0];
        float4 w2 = *(const float4*)&W0m[(kg + 2) * NH + c0];
        float4 w3 = *(const float4*)&W0m[(kg + 3) * NH + c0];
#pragma unroll
        for (int rr = 0; rr < 4; ++rr) {
            float4 hv = *(const float4*)&sh1[(r0 + rr) * DD + kg];
            acc[rr].x = fmaf(hv.x, w0.x, acc[rr].x); acc[rr].x = fmaf(hv.y, w1.x, acc[rr].x);
            acc[rr].x = fmaf(hv.z, w2.x, acc[rr].x); acc[rr].x = fmaf(hv.w, w3.x, acc[rr].x);
            acc[rr].y = fmaf(hv.x, w0.y, acc[rr].y); acc[rr].y = fmaf(hv.y, w1.y, acc[rr].y);
            acc[rr].y = fmaf(hv.z, w2.y, acc[rr].y); acc[rr].y = fmaf(hv.w, w3.y, acc[rr].y);
            acc[rr].z = fmaf(hv.x, w0.z, acc[rr].z); acc[rr].z = fmaf(hv.y, w1.z, acc[rr].z);
            acc[rr].z = fmaf(hv.z, w2.z, acc[rr].z); acc[rr].z = fmaf(hv.w, w3.z, acc[rr].z);
            acc[rr].w = fmaf(hv.x, w0.w, acc[rr].w); acc[rr].w = fmaf(hv.y, w1.w, acc[rr].w);
            acc[rr].w = fmaf(hv.z, w2.w, acc[rr].w); acc[rr].w = fmaf(hv.w, w3.w, acc[rr].w);
        }
    }
    {
        float4 bv = *(const float4*)&b0[c0];
#pragma unroll
        for (int rr = 0; rr < 4; ++rr) {
            float4 o;
            o.x = gelu_f(acc[rr].x + bv.x); o.y = gelu_f(acc[rr].y + bv.y);
            o.z = gelu_f(acc[rr].z + bv.z); o.w = gelu_f(acc[rr].w + bv.w);
            *(float4*)&sh0[(r0 + rr) * NH + c0] = o;
        }
    }
    __syncthreads();

    // ---- GEMM2: h1 = gelu(h0 @ W1m + b1) ----
#pragma unroll
    for (int rr = 0; rr < 4; ++rr) acc[rr] = make_float4(0.f, 0.f, 0.f, 0.f);
#pragma unroll 4
    for (int kg = 0; kg < NH; kg += 4) {
        float4 w0 = *(const float4*)&W1m[(kg + 0) * NH + c0];
        float4 w1 = *(const float4*)&W1m[(kg + 1) * NH + c0];
        float4 w2 = *(const float4*)&W1m[(kg + 2) * NH + c0];
        float4 w3 = *(const float4*)&W1m[(kg + 3) * NH + c0];
#pragma unroll
        for (int rr = 0; rr < 4; ++rr) {
            float4 hv = *(const float4*)&sh0[(r0 + rr) * NH + kg];
            acc[rr].x = fmaf(hv.x, w0.x, acc[rr].x); acc[rr].x = fmaf(hv.y, w1.x, acc[rr].x);
            acc[rr].x = fmaf(hv.z, w2.x, acc[rr].x); acc[rr].x = fmaf(hv.w, w3.x, acc[rr].x);
            acc[rr].y = fmaf(hv.x, w0.y, acc[rr].y); acc[rr].y = fmaf(hv.y, w1.y, acc[rr].y);
            acc[rr].y = fmaf(hv.z, w2.y, acc[rr].y); acc[rr].y = fmaf(hv.w, w3.y, acc[rr].y);
            acc[rr].z = fmaf(hv.x, w0.z, acc[rr].z); acc[rr].z = fmaf(hv.y, w1.z, acc[rr].z);
            acc[rr].z = fmaf(hv.z, w2.z, acc[rr].z); acc[rr].z = fmaf(hv.w, w3.z, acc[rr].z);
            acc[rr].w = fmaf(hv.x, w0.w, acc[rr].w); acc[rr].w = fmaf(hv.y, w1.w, acc[rr].w);
            acc[rr].w = fmaf(hv.z, w2.w, acc[rr].w); acc[rr].w = fmaf(hv.w, w3.w, acc[rr].w);
        }
    }
    {
        float4 bv = *(const float4*)&b1[c0];
#pragma unroll
        for (int rr = 0; rr < 4; ++rr) {
            float4 o;
            o.x = gelu_f(acc[rr].x + bv.x); o.y = gelu_f(acc[rr].y + bv.y);
            o.z = gelu_f(acc[rr].z + bv.z); o.w = gelu_f(acc[rr].w + bv.w);
            *(float4*)&sh1[(r0 + rr) * NH + c0] = o;
        }
    }
    __syncthreads();

    // ---- GEMM3: p[row][per] = h1 . Woutm[i*25+per] + b_out  (RT x 25 outputs into sh0) ----
    for (int o = t; o < RT * PER; o += 256) {
        int row = o / PER;
        int per = o - row * PER;
        int rout = i * PER + per;
        const float* hrow = &sh1[row * NH];
        const float* wrow = &Woutm[rout * NH];
        float dot = 0.f;
#pragma unroll 8
        for (int k = 0; k < NH; k += 4) {
            float4 hv = *(const float4*)&hrow[k];
            float4 wv = *(const float4*)&wrow[k];
            dot = fmaf(hv.x, wv.x, dot); dot = fmaf(hv.y, wv.y, dot);
            dot = fmaf(hv.z, wv.z, dot); dot = fmaf(hv.w, wv.w, dot);
        }
        sh0[o] = dot + b_out[rout];
    }
    __syncthreads();

    // ---- spline inverse, one thread per row ----
    if (t < RT) {
        const int row = row0 + t;
        const float* pp = &sh0[t * PER];
        float pw[8], ph[8], pd[9];
#pragma unroll
        for (int q = 0; q < 8; ++q) pw[q] = pp[q];
#pragma unroll
        for (int q = 0; q < 8; ++q) ph[q] = pp[8 + q];
#pragma unroll
        for (int q = 0; q < 9; ++q) pd[q] = pp[16 + q];

        const float alpha = fminf(fmaxf(((float)(*tstep_p)) / 10000.0f, 0.0f), 1.0f);
        const float oma = 1.0f - alpha;

        float wdt[8], hgt[8];
        // widths
        {
            float m = pw[0];
#pragma unroll
            for (int q = 1; q < 8; ++q) m = fmaxf(m, pw[q]);
            float e[8], s = 0.f;
#pragma unroll
            for (int q = 0; q < 8; ++q) { e[q] = expf(pw[q] - m); s += e[q]; }
            float bw[8], sb = 0.f;
#pragma unroll
            for (int q = 0; q < 8; ++q) {
                float lw = e[q] / s * 9.92f + 0.001f;       // SCALE*(1-K*MIN_BW)+MIN_BW
                bw[q] = oma * 1.25f + alpha * lw;           // (1-a)*SCALE/K
                sb += bw[q];
            }
            float sc = 10.0f / sb;
            float m2 = bw[0] * sc;
#pragma unroll
            for (int q = 0; q < 8; ++q) { bw[q] *= sc; m2 = fmaxf(m2, bw[q]); }
            float s2 = 0.f;
#pragma unroll
            for (int q = 0; q < 8; ++q) { e[q] = expf(bw[q] - m2); s2 += e[q]; }
#pragma unroll
            for (int q = 0; q < 8; ++q) wdt[q] = e[q] / s2 * 9.9992f + 1e-4f;  // SCALE-K*DX_MB
        }
        // heights
        {
            float m = ph[0];
#pragma unroll
            for (int q = 1; q < 8; ++q) m = fmaxf(m, ph[q]);
            float e[8], s = 0.f;
#pragma unroll
            for (int q = 0; q < 8; ++q) { e[q] = expf(ph[q] - m); s += e[q]; }
            float bh[8], sb = 0.f;
#pragma unroll
            for (int q = 0; q < 8; ++q) {
                float lh = e[q] / s * 9.92f + 0.001f;
                bh[q] = oma * 1.25f + alpha * lh;
                sb += bh[q];
            }
            float sc = 10.0f / sb;
            float m2 = bh[0] * sc;
#pragma unroll
            for (int q = 0; q < 8; ++q) { bh[q] *= sc; m2 = fmaxf(m2, bh[q]); }
            float s2 = 0.f;
#pragma unroll
            for (int q = 0; q < 8; ++q) { e[q] = expf(bh[q] - m2); s2 += e[q]; }
#pragma unroll
            for (int q = 0; q < 8; ++q) hgt[q] = e[q] / s2 * 9.9992f + 1e-4f;
        }
        // slopes
        float dd_[9];
        {
            const float dxoff = logf(expm1f(0.9999f));      // DX_OFF
#pragma unroll
            for (int q = 0; q < 9; ++q) {
                float ls = softplus_f(pd[q]) + 0.001f;
                float sl = oma + alpha * ls;
                dd_[q] = softplus_f(sl + dxoff) + 1e-4f;
            }
        }
        // knots
        float xp[9], yp[9];
        xp[0] = -5.0f; yp[0] = -5.0f;
        {
            float cx = 0.f, cy = 0.f;
#pragma unroll
            for (int q = 0; q < 8; ++q) {
                cx += wdt[q]; xp[q + 1] = -5.0f + cx;
                cy += hgt[q]; yp[q + 1] = -5.0f + cy;
            }
        }

        const float zi = z[row * DD + i];
        const bool inr = (zi >= -5.0f) && (zi <= 5.0f);
        const float yc = fminf(fmaxf(zi, -5.0f), 5.0f);

        float xk = xp[0], yk = yp[0], wk = wdt[0], hk = hgt[0], dk = dd_[0], dk1 = dd_[1];
#pragma unroll
        for (int q = 1; q < 8; ++q) {
            bool c = (yc >= yp[q]);
            xk = c ? xp[q] : xk;  yk = c ? yp[q] : yk;
            wk = c ? wdt[q] : wk; hk = c ? hgt[q] : hk;
            dk = c ? dd_[q] : dk; dk1 = c ? dd_[q + 1] : dk1;
        }

        float s_ = hk / wk;
        float tt = yc - yk;
        float coef = dk1 + dk - 2.0f * s_;
        float aa = hk * (s_ - dk) + tt * coef;
        float bb = hk * dk - tt * coef;
        float cc = -s_ * tt;
        float disc = bb * bb - 4.0f * aa * cc;
        float xi = 2.0f * cc / (-bb - sqrtf(disc));
        float xv = xi * wk + xk;
        float z1 = xi * (1.0f - xi);
        float den = s_ + coef * z1;
        float omxi = 1.0f - xi;
        float ld = -(2.0f * logf(s_) + logf(dk1 * xi * xi + 2.0f * s_ * z1 + dk * omxi * omxi)
                     - 2.0f * logf(den));

        xout[row * DD + i] = inr ? xv : zi;
        ldj[row] += inr ? ld : 0.0f;
    }
}

extern "C" void kernel_launch(void* const* d_in, const int* in_sizes, int n_in,
                              void* d_out, int out_size, void* d_ws, size_t ws_size,
                              hipStream_t stream)
{
    const float* z    = (const float*)d_in[0];
    const float* W0   = (const float*)d_in[1];
    const float* b0   = (const float*)d_in[2];
    const float* W1   = (const float*)d_in[3];
    const float* b1   = (const float*)d_in[4];
    const float* Wout = (const float*)d_in[5];
    const float* bout = (const float*)d_in[6];
    const int* tstep  = (const int*)d_in[8];

    float* out  = (float*)d_out;
    float* xout = out;                 // x_fin, B x D (also the autoregressive state)
    float* ldj  = out + NB * DD;       // ldj, B

    float* wsf   = (float*)d_ws;
    float* W0m   = wsf;                          // 8192
    float* W1m   = wsf + 8192;                   // 65536
    float* Woutm = wsf + 8192 + 65536;           // 204800

    prep_kernel<<<1088, 256, 0, stream>>>(W0, W1, Wout, W0m, W1m, Woutm, ldj);
    for (int i = 0; i < DD; ++i) {
        step_kernel<<<NB / RT, 256, 0, stream>>>(i, z, W0m, b0, W1m, b1, Woutm, bout,
                                                 tstep, xout, ldj);
    }
}

// Round 2
// 536.418 us; speedup vs baseline: 4.7407x; 4.7407x over previous
//
#include <hip/hip_runtime.h>

#define NB 8192      // batch
#define DD 32        // dims
#define NH 256       // hidden
#define PER 25       // 3*K+1
#define RT 16        // rows per block

__device__ __forceinline__ float gelu_f(float x) {
    float x3 = x * x * x;
    return 0.5f * x * (1.0f + tanhf(0.7978845608028654f * (x + 0.044715f * x3)));
}
__device__ __forceinline__ float softplus_f(float x) {
    return (x > 20.0f) ? x : log1pf(expf(x));
}
// # hidden units with degree <= d (degrees 1..31; 256 = 31*8 + 8 -> degs 1..8 have 9 units)
__device__ __forceinline__ int cntf(int d) {
    return (d <= 0) ? 0 : ((d <= 8) ? 9 * d : 72 + 8 * (d - 8));
}
// stable degree-sort position of original hidden index j (hd = j%31+1)
__device__ __forceinline__ int posmap(int j) {
    int d = j % 31 + 1;
    int s = j / 31;
    return cntf(d - 1) + s;
}

// Pure-permutation weight prep (no masking needed: all prefix-accessed weights have mask==1).
// W0T[pos(j)][c]  = W0[c][j]          (256 x 32)
// W1T[pos(j1)][pos(k0)] = W1[k0][j1]  (256 x 256)
// WoutP[rout][pos(j)] = Wout[rout][j] (800 x 256)
// b0P[pos(j)] = b0[j]; b1P[pos(j)] = b1[j]
__global__ void prep_kernel(const float* __restrict__ W0, const float* __restrict__ b0,
                            const float* __restrict__ W1, const float* __restrict__ b1,
                            const float* __restrict__ Wout,
                            float* __restrict__ W0T, float* __restrict__ b0P,
                            float* __restrict__ W1T, float* __restrict__ b1P,
                            float* __restrict__ WoutP)
{
    const int total = 8192 + 65536 + 204800 + 256 + 256;
    for (int idx = blockIdx.x * blockDim.x + threadIdx.x; idx < total;
         idx += gridDim.x * blockDim.x) {
        if (idx < 8192) {
            int c = idx >> 8, j = idx & 255;
            W0T[posmap(j) * 32 + c] = W0[idx];
        } else if (idx < 8192 + 65536) {
            int m = idx - 8192;
            int k0 = m >> 8, j1 = m & 255;
            W1T[posmap(j1) * 256 + posmap(k0)] = W1[m];
        } else if (idx < 8192 + 65536 + 204800) {
            int m = idx - (8192 + 65536);
            int r = m >> 8, j = m & 255;
            WoutP[r * 256 + posmap(j)] = Wout[m];
        } else if (idx < 8192 + 65536 + 204800 + 256) {
            int j = idx - (8192 + 65536 + 204800);
            b0P[posmap(j)] = b0[j];
        } else {
            int j = idx - (8192 + 65536 + 204800 + 256);
            b1P[posmap(j)] = b1[j];
        }
    }
}

// Persistent inverse: each block owns RT rows through all 32 AR steps, state in LDS.
__global__ __launch_bounds__(256) void inv_kernel(
    const float* __restrict__ z,
    const float* __restrict__ W0T, const float* __restrict__ b0P,
    const float* __restrict__ W1T, const float* __restrict__ b1P,
    const float* __restrict__ WoutP, const float* __restrict__ b_out,
    const int* __restrict__ tstep_p,
    float* __restrict__ xout, float* __restrict__ ldj)
{
    __shared__ float xs[RT * 33];                      // x state (padded)
    __shared__ float zs[RT * 33];                      // staged z tile
    __shared__ __align__(16) float h0s[RT * 260];      // degree-sorted h0 (padded stride)
    __shared__ __align__(16) float h1s[RT * 260];      // degree-sorted h1
    __shared__ float ps[RT * 27];                      // spline params per row

    const int t = threadIdx.x;
    const int row0 = blockIdx.x * RT;

    // stage z tile (RT x 32)
    for (int idx = t; idx < RT * 32; idx += 256) {
        int r = idx >> 5, c = idx & 31;
        zs[r * 33 + c] = z[(row0 + r) * 32 + c];
    }
    __syncthreads();

    const int r = t & 15;       // row within tile
    const int g = t >> 4;       // unit-group index 0..15

    const float alpha = fminf(fmaxf(((float)(*tstep_p)) / 10000.0f, 0.0f), 1.0f);
    const float oma = 1.0f - alpha;
    const float dxoff = logf(expm1f(0.9999f));   // DX_OFF

    float ldreg = 0.0f;

    for (int i = 0; i < DD; ++i) {
        const int c_lo = cntf(i - 1);
        const int c_hi = cntf(i);
        const int nn = c_hi - c_lo;     // new units this step (8 or 9), 0 at i=0

        // ---- Phase A: new h0 units (hd0 == i), final values ----
        if (i >= 1 && g < nn) {
            float acc = b0P[c_lo + g];
            const float* __restrict__ w = &W0T[(c_lo + g) * 32];
            const float* __restrict__ xr = &xs[r * 33];
            for (int c = 0; c < i; ++c) acc = fmaf(xr[c], w[c], acc);
            h0s[r * 260 + c_lo + g] = gelu_f(acc);
        }
        __syncthreads();

        // ---- Phase B: new h1 units (hd1 == i), over h0 prefix cnt0(i) ----
        if (i >= 1 && g < nn) {
            float acc = b1P[c_lo + g];
            const float* __restrict__ w = &W1T[(c_lo + g) * 256];
            const float* __restrict__ h = &h0s[r * 260];
            const int K = c_hi;
            int k = 0;
            for (; k + 4 <= K; k += 4) {
                float4 hv = *(const float4*)&h[k];
                float4 wv = *(const float4*)&w[k];
                acc = fmaf(hv.x, wv.x, acc); acc = fmaf(hv.y, wv.y, acc);
                acc = fmaf(hv.z, wv.z, acc); acc = fmaf(hv.w, wv.w, acc);
            }
            for (; k < K; ++k) acc = fmaf(h[k], w[k], acc);
            h1s[r * 260 + c_lo + g] = gelu_f(acc);
        }
        __syncthreads();

        // ---- Phase C: p[row][25] over h1 prefix cnt1(i) ----
        {
            const int J = c_hi;
            for (int o = t; o < RT * PER; o += 256) {
                int rr = o & 15, pr = o >> 4;
                float acc = b_out[i * PER + pr];
                const float* __restrict__ w = &WoutP[(i * PER + pr) * 256];
                const float* __restrict__ h = &h1s[rr * 260];
                int j = 0;
                for (; j + 4 <= J; j += 4) {
                    float4 hv = *(const float4*)&h[j];
                    float4 wv = *(const float4*)&w[j];
                    acc = fmaf(hv.x, wv.x, acc); acc = fmaf(hv.y, wv.y, acc);
                    acc = fmaf(hv.z, wv.z, acc); acc = fmaf(hv.w, wv.w, acc);
                }
                for (; j < J; ++j) acc = fmaf(h[j], w[j], acc);
                ps[rr * 27 + pr] = acc;
            }
        }
        __syncthreads();

        // ---- Spline inverse: one thread per row ----
        if (t < RT) {
            const float* pp = &ps[t * 27];
            float pw[8], ph[8], pd[9];
#pragma unroll
            for (int q = 0; q < 8; ++q) pw[q] = pp[q];
#pragma unroll
            for (int q = 0; q < 8; ++q) ph[q] = pp[8 + q];
#pragma unroll
            for (int q = 0; q < 9; ++q) pd[q] = pp[16 + q];

            float wdt[8], hgt[8];
            // widths
            {
                float m = pw[0];
#pragma unroll
                for (int q = 1; q < 8; ++q) m = fmaxf(m, pw[q]);
                float e[8], s = 0.f;
#pragma unroll
                for (int q = 0; q < 8; ++q) { e[q] = expf(pw[q] - m); s += e[q]; }
                float bw[8], sb = 0.f;
#pragma unroll
                for (int q = 0; q < 8; ++q) {
                    float lw = e[q] / s * 9.92f + 0.001f;
                    bw[q] = oma * 1.25f + alpha * lw;
                    sb += bw[q];
                }
                float sc = 10.0f / sb;
                float m2 = bw[0] * sc;
#pragma unroll
                for (int q = 0; q < 8; ++q) { bw[q] *= sc; m2 = fmaxf(m2, bw[q]); }
                float s2 = 0.f;
#pragma unroll
                for (int q = 0; q < 8; ++q) { e[q] = expf(bw[q] - m2); s2 += e[q]; }
#pragma unroll
                for (int q = 0; q < 8; ++q) wdt[q] = e[q] / s2 * 9.9992f + 1e-4f;
            }
            // heights
            {
                float m = ph[0];
#pragma unroll
                for (int q = 1; q < 8; ++q) m = fmaxf(m, ph[q]);
                float e[8], s = 0.f;
#pragma unroll
                for (int q = 0; q < 8; ++q) { e[q] = expf(ph[q] - m); s += e[q]; }
                float bh[8], sb = 0.f;
#pragma unroll
                for (int q = 0; q < 8; ++q) {
                    float lh = e[q] / s * 9.92f + 0.001f;
                    bh[q] = oma * 1.25f + alpha * lh;
                    sb += bh[q];
                }
                float sc = 10.0f / sb;
                float m2 = bh[0] * sc;
#pragma unroll
                for (int q = 0; q < 8; ++q) { bh[q] *= sc; m2 = fmaxf(m2, bh[q]); }
                float s2 = 0.f;
#pragma unroll
                for (int q = 0; q < 8; ++q) { e[q] = expf(bh[q] - m2); s2 += e[q]; }
#pragma unroll
                for (int q = 0; q < 8; ++q) hgt[q] = e[q] / s2 * 9.9992f + 1e-4f;
            }
            // slopes
            float dd_[9];
#pragma unroll
            for (int q = 0; q < 9; ++q) {
                float ls = softplus_f(pd[q]) + 0.001f;
                float sl = oma + alpha * ls;
                dd_[q] = softplus_f(sl + dxoff) + 1e-4f;
            }
            // knots
            float xp[9], yp[9];
            xp[0] = -5.0f; yp[0] = -5.0f;
            {
                float cx = 0.f, cy = 0.f;
#pragma unroll
                for (int q = 0; q < 8; ++q) {
                    cx += wdt[q]; xp[q + 1] = -5.0f + cx;
                    cy += hgt[q]; yp[q + 1] = -5.0f + cy;
                }
            }

            const float zi = zs[t * 33 + i];
            const bool inr = (zi >= -5.0f) && (zi <= 5.0f);
            const float yc = fminf(fmaxf(zi, -5.0f), 5.0f);

            float xk = xp[0], yk = yp[0], wk = wdt[0], hk = hgt[0], dk = dd_[0], dk1 = dd_[1];
#pragma unroll
            for (int q = 1; q < 8; ++q) {
                bool c = (yc >= yp[q]);
                xk = c ? xp[q] : xk;  yk = c ? yp[q] : yk;
                wk = c ? wdt[q] : wk; hk = c ? hgt[q] : hk;
                dk = c ? dd_[q] : dk; dk1 = c ? dd_[q + 1] : dk1;
            }

            float s_ = hk / wk;
            float tt = yc - yk;
            float coef = dk1 + dk - 2.0f * s_;
            float aa = hk * (s_ - dk) + tt * coef;
            float bb = hk * dk - tt * coef;
            float cc = -s_ * tt;
            float disc = bb * bb - 4.0f * aa * cc;
            float xi = 2.0f * cc / (-bb - sqrtf(disc));
            float xv = xi * wk + xk;
            float z1 = xi * (1.0f - xi);
            float den = s_ + coef * z1;
            float omxi = 1.0f - xi;
            float ld = -(2.0f * logf(s_) + logf(dk1 * xi * xi + 2.0f * s_ * z1 + dk * omxi * omxi)
                         - 2.0f * logf(den));

            xs[t * 33 + i] = inr ? xv : zi;
            ldreg += inr ? ld : 0.0f;
        }
        __syncthreads();
    }

    // write outputs
    for (int idx = t; idx < RT * 32; idx += 256) {
        int rr = idx >> 5, c = idx & 31;
        xout[(row0 + rr) * 32 + c] = xs[rr * 33 + c];
    }
    if (t < RT) ldj[row0 + t] = ldreg;
}

extern "C" void kernel_launch(void* const* d_in, const int* in_sizes, int n_in,
                              void* d_out, int out_size, void* d_ws, size_t ws_size,
                              hipStream_t stream)
{
    const float* z    = (const float*)d_in[0];
    const float* W0   = (const float*)d_in[1];
    const float* b0   = (const float*)d_in[2];
    const float* W1   = (const float*)d_in[3];
    const float* b1   = (const float*)d_in[4];
    const float* Wout = (const float*)d_in[5];
    const float* bout = (const float*)d_in[6];
    const int* tstep  = (const int*)d_in[8];

    float* out  = (float*)d_out;
    float* xout = out;                 // x_fin, B x D
    float* ldj  = out + NB * DD;       // ldj, B

    float* wsf   = (float*)d_ws;
    float* W0T   = wsf;                          // 8192
    float* W1T   = wsf + 8192;                   // 65536
    float* WoutP = wsf + 8192 + 65536;           // 204800
    float* b0P   = wsf + 8192 + 65536 + 204800;  // 256
    float* b1P   = b0P + 256;                    // 256

    prep_kernel<<<1090, 256, 0, stream>>>(W0, b0, W1, b1, Wout, W0T, b0P, W1T, b1P, WoutP);
    inv_kernel<<<NB / RT, 256, 0, stream>>>(z, W0T, b0P, W1T, b1P, WoutP, bout,
                                            tstep, xout, ldj);
}

// Round 3
// 415.427 us; speedup vs baseline: 6.1214x; 1.2912x over previous
//
#include <hip/hip_runtime.h>

#define NB 8192
#define DD 32
#define PER 25
#define WSTRIDE 576   // floats per wave LDS region: h0[256] h1[256] xs[32] ps[28] pad

// wave-internal LDS fence: drain own LDS ops + stop compiler reordering
#define FENCE() do { asm volatile("s_waitcnt lgkmcnt(0)" ::: "memory"); \
                     __builtin_amdgcn_sched_barrier(0); } while (0)

__device__ __forceinline__ float gelu_f(float x) {
    float x3 = x * x * x;
    return 0.5f * x * (1.0f + tanhf(0.7978845608028654f * (x + 0.044715f * x3)));
}
__device__ __forceinline__ float softplus_f(float x) {
    return (x > 20.0f) ? x : log1pf(expf(x));
}
// # hidden units with degree <= d (degrees 1..31; degs 1..8 have 9 units, rest 8)
__device__ __forceinline__ int cntf(int d) {
    return (d <= 0) ? 0 : ((d <= 8) ? 9 * d : 72 + 8 * (d - 8));
}
// stable degree-sort position of original hidden index j (deg = j%31+1)
__device__ __forceinline__ int posmap(int j) {
    int d = j % 31 + 1;
    int s = j / 31;
    return cntf(d - 1) + s;
}

// Permute AND mask weights (masked entries -> exact 0 so padded K-ranges are safe).
__global__ void prep_kernel(const float* __restrict__ W0, const float* __restrict__ b0,
                            const float* __restrict__ W1, const float* __restrict__ b1,
                            const float* __restrict__ Wout,
                            float* __restrict__ W0T, float* __restrict__ b0P,
                            float* __restrict__ W1T, float* __restrict__ b1P,
                            float* __restrict__ WoutP)
{
    const int total = 8192 + 65536 + 204800 + 256 + 256;
    for (int idx = blockIdx.x * blockDim.x + threadIdx.x; idx < total;
         idx += gridDim.x * blockDim.x) {
        if (idx < 8192) {
            int c = idx >> 8, j = idx & 255;
            int d = j % 31 + 1;                      // hd0
            W0T[posmap(j) * 32 + c] = (c < d) ? W0[idx] : 0.0f;
        } else if (idx < 8192 + 65536) {
            int m = idx - 8192;
            int k0 = m >> 8, j1 = m & 255;
            int dk = k0 % 31 + 1, dj = j1 % 31 + 1;
            W1T[posmap(j1) * 256 + posmap(k0)] = (dk <= dj) ? W1[m] : 0.0f;
        } else if (idx < 8192 + 65536 + 204800) {
            int m = idx - (8192 + 65536);
            int r = m >> 8, j = m & 255;
            int dj = j % 31 + 1;
            WoutP[r * 256 + posmap(j)] = (dj <= r / PER) ? Wout[m] : 0.0f;
        } else if (idx < 8192 + 65536 + 204800 + 256) {
            int j = idx - (8192 + 65536 + 204800);
            b0P[posmap(j)] = b0[j];
        } else {
            int j = idx - (8192 + 65536 + 204800 + 256);
            b1P[posmap(j)] = b1[j];
        }
    }
}

// One wave per row; 4 waves per block, fully independent (no block barriers).
__global__ __launch_bounds__(256) void inv_kernel(
    const float* __restrict__ z,
    const float* __restrict__ W0T, const float* __restrict__ b0P,
    const float* __restrict__ W1T, const float* __restrict__ b1P,
    const float* __restrict__ WoutP, const float* __restrict__ b_out,
    const int* __restrict__ tstep_p,
    float* __restrict__ xout, float* __restrict__ ldj)
{
    __shared__ __align__(16) float sh[4 * WSTRIDE];
    const int t = threadIdx.x;
    const int l = t & 63;          // lane in wave
    const int w = t >> 6;          // wave id in block
    const int row = blockIdx.x * 4 + w;

    float* h0s = &sh[w * WSTRIDE];       // [256]
    float* h1s = h0s + 256;              // [256]
    float* xs  = h0s + 512;              // [32]
    float* ps  = h0s + 544;              // [28]

    // zero-init h0/h1 so padded K-ranges read exact zeros
    h0s[l] = 0.0f; h0s[l + 64] = 0.0f; h0s[l + 128] = 0.0f; h0s[l + 192] = 0.0f;
    h1s[l] = 0.0f; h1s[l + 64] = 0.0f; h1s[l + 128] = 0.0f; h1s[l + 192] = 0.0f;

    const float zreg = z[row * 32 + (l & 31)];

    const float alpha = fminf(fmaxf(((float)(*tstep_p)) / 10000.0f, 0.0f), 1.0f);
    const float oma = 1.0f - alpha;
    const float dxoff = logf(expm1f(0.9999f));   // DX_OFF

    float ldreg = 0.0f;
    FENCE();

    for (int i = 0; i < DD; ++i) {
        const int c_lo = cntf(i - 1);
        const int c_hi = cntf(i);
        const int nn = c_hi - c_lo;          // 0 at i=0, else 8 or 9

        // ---- Phase A: new h0 units (deg == i), one lane per unit ----
        if (l < nn) {
            const int u = c_lo + l;
            float acc = b0P[u];
            const float* __restrict__ wr = &W0T[u * 32];
            for (int c = 0; c < i; ++c) acc = fmaf(xs[c], wr[c], acc);
            h0s[u] = gelu_f(acc);
        }
        FENCE();

        // ---- Phase B: new h1 units over h0 prefix, 4 lanes per unit ----
        if (l < 4 * nn) {
            const int u = c_lo + (l >> 2);
            const int p = l & 3;
            const float4* __restrict__ wr = (const float4*)&W1T[u * 256];
            const float4* __restrict__ hr = (const float4*)h0s;
            const int KP = (c_hi + 15) >> 4;          // 16-float chunks
            float4 a4 = make_float4(0.f, 0.f, 0.f, 0.f);
            for (int j = 0; j < KP; ++j) {
                float4 hv = hr[j * 4 + p];
                float4 wv = wr[j * 4 + p];
                a4.x = fmaf(hv.x, wv.x, a4.x); a4.y = fmaf(hv.y, wv.y, a4.y);
                a4.z = fmaf(hv.z, wv.z, a4.z); a4.w = fmaf(hv.w, wv.w, a4.w);
            }
            float acc = (a4.x + a4.y) + (a4.z + a4.w);
            acc += __shfl_xor(acc, 1);
            acc += __shfl_xor(acc, 2);
            if (p == 0) h1s[u] = gelu_f(acc + b1P[u]);
        }
        FENCE();

        // ---- Phase C: 25 outputs over h1 prefix, 2 lanes per dot ----
        if (l < 2 * PER) {
            const int d = l >> 1;
            const int p = l & 1;
            const float4* __restrict__ wr = (const float4*)&WoutP[(i * PER + d) * 256];
            const float4* __restrict__ hr = (const float4*)h1s;
            const int KP2 = (c_hi + 7) >> 3;          // 8-float chunks
            float4 a4 = make_float4(0.f, 0.f, 0.f, 0.f);
            for (int j = 0; j < KP2; ++j) {
                float4 hv = hr[j * 2 + p];
                float4 wv = wr[j * 2 + p];
                a4.x = fmaf(hv.x, wv.x, a4.x); a4.y = fmaf(hv.y, wv.y, a4.y);
                a4.z = fmaf(hv.z, wv.z, a4.z); a4.w = fmaf(hv.w, wv.w, a4.w);
            }
            float acc = (a4.x + a4.y) + (a4.z + a4.w);
            acc += __shfl_xor(acc, 1);
            if (p == 0) ps[d] = acc + b_out[i * PER + d];
        }
        FENCE();

        // ---- Spline inverse (lane-parallel) ----
        {
            float smo = 0.0f, cum = 0.0f;   // per-lane softmax out / inclusive scan
            if (l < 16) {   // lanes 0-7: widths; 8-15: heights (same code path)
                float v = ps[l];
                float m = v;
                m = fmaxf(m, __shfl_xor(m, 1));
                m = fmaxf(m, __shfl_xor(m, 2));
                m = fmaxf(m, __shfl_xor(m, 4));
                float e = expf(v - m);
                float s = e;
                s += __shfl_xor(s, 1); s += __shfl_xor(s, 2); s += __shfl_xor(s, 4);
                float lw = e / s * 9.92f + 0.001f;            // SCALE*(1-K*MIN)+MIN
                float bwv = oma * 1.25f + alpha * lw;         // (1-a)*SCALE/K + a*lw
                float sb = bwv;
                sb += __shfl_xor(sb, 1); sb += __shfl_xor(sb, 2); sb += __shfl_xor(sb, 4);
                bwv *= 10.0f / sb;
                float m2 = bwv;
                m2 = fmaxf(m2, __shfl_xor(m2, 1));
                m2 = fmaxf(m2, __shfl_xor(m2, 2));
                m2 = fmaxf(m2, __shfl_xor(m2, 4));
                float e2 = expf(bwv - m2);
                float s2 = e2;
                s2 += __shfl_xor(s2, 1); s2 += __shfl_xor(s2, 2); s2 += __shfl_xor(s2, 4);
                smo = e2 / s2 * 9.9992f + 1e-4f;              // SCALE-K*DX_MB
                // inclusive prefix scan within each 8-lane group
                cum = smo;
                float tv;
                tv = __shfl_up(cum, 1); if ((l & 7) >= 1) cum += tv;
                tv = __shfl_up(cum, 2); if ((l & 7) >= 2) cum += tv;
                tv = __shfl_up(cum, 4); if ((l & 7) >= 4) cum += tv;
            }
            float ddv = 0.0f;
            if (l >= 16 && l < 25) {   // 9 slopes, fully parallel
                float ls = softplus_f(ps[l]) + 0.001f;
                float sl = oma + alpha * ls;
                ddv = softplus_f(sl + dxoff) + 1e-4f;
            }

            const float zi = __shfl(zreg, i);
            const bool inr = (zi >= -5.0f) && (zi <= 5.0f);
            const float yc = fminf(fmaxf(zi, -5.0f), 5.0f);

            // bin index: popcount of (yc >= yp[k]) for k=1..7 (lanes 8..14 hold yp[j+1]-(-5))
            bool bc = (l >= 8 && l <= 14) && (yc >= (cum - 5.0f));
            unsigned long long ball = __ballot(bc);
            int idx = __popcll(ball);                 // 0..7

            float wk = __shfl(smo, idx);
            float hk = __shfl(smo, 8 + idx);
            int sx = (idx == 0) ? 0 : (idx - 1);
            float cxm = __shfl(cum, sx);
            float cym = __shfl(cum, 8 + sx);
            float xk = (idx == 0) ? -5.0f : (cxm - 5.0f);
            float yk = (idx == 0) ? -5.0f : (cym - 5.0f);
            float dk  = __shfl(ddv, 16 + idx);
            float dk1 = __shfl(ddv, 17 + idx);

            float s_ = hk / wk;
            float tt = yc - yk;
            float coef = dk1 + dk - 2.0f * s_;
            float aa = hk * (s_ - dk) + tt * coef;
            float bb = hk * dk - tt * coef;
            float cc = -s_ * tt;
            float disc = bb * bb - 4.0f * aa * cc;
            float xi = 2.0f * cc / (-bb - sqrtf(disc));
            float xv = xi * wk + xk;
            float z1 = xi * (1.0f - xi);
            float den = s_ + coef * z1;
            float omxi = 1.0f - xi;
            float ld = -(2.0f * logf(s_) + logf(dk1 * xi * xi + 2.0f * s_ * z1 + dk * omxi * omxi)
                         - 2.0f * logf(den));

            ldreg += inr ? ld : 0.0f;
            if (l == 0) xs[i] = inr ? xv : zi;
        }
        FENCE();
    }

    if (l < 32) xout[row * 32 + l] = xs[l];
    if (l == 0) ldj[row] = ldreg;
}

extern "C" void kernel_launch(void* const* d_in, const int* in_sizes, int n_in,
                              void* d_out, int out_size, void* d_ws, size_t ws_size,
                              hipStream_t stream)
{
    const float* z    = (const float*)d_in[0];
    const float* W0   = (const float*)d_in[1];
    const float* b0   = (const float*)d_in[2];
    const float* W1   = (const float*)d_in[3];
    const float* b1   = (const float*)d_in[4];
    const float* Wout = (const float*)d_in[5];
    const float* bout = (const float*)d_in[6];
    const int* tstep  = (const int*)d_in[8];

    float* out  = (float*)d_out;
    float* xout = out;                 // x_fin, B x D
    float* ldj  = out + NB * DD;       // ldj, B

    float* wsf   = (float*)d_ws;
    float* W0T   = wsf;                          // 8192
    float* W1T   = wsf + 8192;                   // 65536
    float* WoutP = wsf + 8192 + 65536;           // 204800
    float* b0P   = wsf + 8192 + 65536 + 204800;  // 256
    float* b1P   = b0P + 256;                    // 256

    prep_kernel<<<1090, 256, 0, stream>>>(W0, b0, W1, b1, Wout, W0T, b0P, W1T, b1P, WoutP);
    inv_kernel<<<NB / 4, 256, 0, stream>>>(z, W0T, b0P, W1T, b1P, WoutP, bout,
                                           tstep, xout, ldj);
}